// Round 1
// baseline (4080.969 us; speedup 1.0000x reference)
//
#include <hip/hip_runtime.h>
#include <math.h>

#define NN 32
#define DTC 0.01f
#define NSTEPS 10
#define M_ITEMS 8192
#define H_DIM 4096
#define TWO_PI_F 6.28318530717958648f
#define INV_2PI 0.15915494309189535f

__device__ __forceinline__ float dpp_shr1(float v) {  // lane i <- s[i-1], 0 at row starts
  int r = __builtin_amdgcn_update_dpp(0, __builtin_bit_cast(int, v), 0x111, 0xf, 0xf, true);
  return __builtin_bit_cast(float, r);
}
__device__ __forceinline__ float dpp_shl1(float v) {  // lane i <- s[i+1], 0 at row ends
  int r = __builtin_amdgcn_update_dpp(0, __builtin_bit_cast(int, v), 0x101, 0xf, 0xf, true);
  return __builtin_bit_cast(float, r);
}
__device__ __forceinline__ float rdlane(float v, int l) {
  return __builtin_bit_cast(float, __builtin_amdgcn_readlane(__builtin_bit_cast(int, v), l));
}

// ---------------- GEMM1: ext[m,n] = tanh(b1[n] + sum_k x[m,k] * W1[k,n]) ----------------
// grid 1024, block 256. Block handles 8 rows; wave w covers k in [w*1024, w*1024+1024),
// lane: n = lane&31, half = lane>>5 takes 512 k's. 8 partials reduced via LDS.
__global__ __launch_bounds__(256) void gemm1_kernel(const float* __restrict__ x,
                                                    const float* __restrict__ W1,
                                                    const float* __restrict__ b1,
                                                    float* __restrict__ ext) {
  __shared__ float part[8][8][NN];
  const int t = threadIdx.x;
  const int wave = t >> 6, lane = t & 63;
  const int n = lane & 31, half = lane >> 5;
  const int r0 = blockIdx.x * 8;
  const int kbase = wave * 1024 + half * 512;
  float acc[8] = {0.f, 0.f, 0.f, 0.f, 0.f, 0.f, 0.f, 0.f};
  const float* xp = x + (size_t)r0 * H_DIM + kbase;
  const float* wp = W1 + (size_t)kbase * NN + n;
#pragma unroll 4
  for (int kk = 0; kk < 512; ++kk) {
    float wv = wp[kk * NN];
#pragma unroll
    for (int j = 0; j < 8; ++j) acc[j] = fmaf(xp[(size_t)j * H_DIM + kk], wv, acc[j]);
  }
#pragma unroll
  for (int j = 0; j < 8; ++j) part[wave * 2 + half][j][n] = acc[j];
  __syncthreads();
  {
    const int j = t >> 5, n2 = t & 31;
    float s = b1[n2];
#pragma unroll
    for (int pi = 0; pi < 8; ++pi) s += part[pi][j][n2];
    ext[(r0 + j) * NN + n2] = tanhf(s);
  }
}

// ---------------- Scan: serial coupled-oscillator recurrence ----------------
// 1 block, 64 threads. Lane = node (nodes on lanes 0..31; lanes 32..63 mirror, unused).
// State: q = wrapped phase in revolutions, p = raw accumulated radians, a = amplitude.
__global__ __launch_bounds__(64, 1) void scan_kernel(const float* __restrict__ ext,
                                                     const float* __restrict__ init_phase,
                                                     float* __restrict__ st) {
  const int lane = threadIdx.x;
  const int node = lane & 31;
  const float f = 1.0f + (float)node * (0.5f / 32.0f);
  const float basef_q = DTC * f;              // rev advance from frequency
  const float kq = DTC * 0.5f * INV_2PI;      // coupling -> rev
  const float c_e2q = DTC * INV_2PI;          // ext -> rev
  float p = init_phase[node];
  float q = p * INV_2PI;
  q = q - floorf(q);
  float a = 0.1f;
  const bool is15 = (lane == 15);
  const bool is16 = (lane == 16);
  float e = ext[node];
  for (int it = 0; it < M_ITEMS; ++it) {
    float e_nxt = (it + 1 < M_ITEMS) ? ext[(it + 1) * NN + node] : 0.0f;  // prefetch
    const float base_q = fmaf(c_e2q, e, basef_q);  // per-step rev advance (const over item)
    const float dext = DTC * e;
#pragma unroll
    for (int si = 0; si < NSTEPS; ++si) {
      float sv = __builtin_amdgcn_sinf(q);       // sin(2*pi*q) = sin(p)
      float qb = q + base_q;                     // off critical path
      float s = a * sv;
      float sl = dpp_shr1(s);
      float sr = dpp_shl1(s);
      float s15 = rdlane(s, 15);
      float s16 = rdlane(s, 16);
      sl = is16 ? s15 : sl;                      // patch row boundary 15|16
      sr = is15 ? s16 : sr;
      float coup = sl + sr;                      // (a*sin)@Wc / 0.5
      float dq = fmaf(kq, coup, base_q);         // total rev delta this step
      p = fmaf(TWO_PI_F, dq, p);                 // raw radians for output (side chain)
      float qn = fmaf(kq, coup, qb);             // q + dq
      q = __builtin_amdgcn_fractf(qn);           // wrapped
      float cv = __builtin_amdgcn_cosf(q);       // cos(p_new)
      a = fminf(fmaxf(fmaf(dext, cv, a), 0.0f), 1.0f);
    }
    if (lane < NN) {
      st[it * 64 + node] = p;
      st[it * 64 + 32 + node] = a;
    }
    e = e_nxt;
  }
}

// ---------------- GEMM2: out[m,h] = x[m,h] + b2[h] + sum_j st[m,j]*W2[j,h] ----------------
// grid (16,128), block 256. Tile 64 rows x 256 cols; st tile staged in LDS.
__global__ __launch_bounds__(256) void gemm2_kernel(const float* __restrict__ x,
                                                    const float* __restrict__ W2,
                                                    const float* __restrict__ b2,
                                                    const float* __restrict__ st,
                                                    float* __restrict__ out) {
  __shared__ float sst[64 * 64];
  const int t = threadIdx.x;
  const int cbase = blockIdx.x * 256;
  const int rbase = blockIdx.y * 64;
  const float4* src = (const float4*)(st + (size_t)rbase * 64);
  float4* dst4 = (float4*)sst;
#pragma unroll
  for (int i = 0; i < 4; ++i) dst4[i * 256 + t] = src[i * 256 + t];
  __syncthreads();
  const int tq = t & 63, rg = t >> 6;
  const int h0 = cbase + tq * 4;
  float4 acc[16];
#pragma unroll
  for (int i = 0; i < 16; ++i) acc[i] = make_float4(0.f, 0.f, 0.f, 0.f);
  for (int j4 = 0; j4 < 16; ++j4) {
    float4 w0 = *(const float4*)(W2 + (size_t)(j4 * 4 + 0) * H_DIM + h0);
    float4 w1 = *(const float4*)(W2 + (size_t)(j4 * 4 + 1) * H_DIM + h0);
    float4 w2 = *(const float4*)(W2 + (size_t)(j4 * 4 + 2) * H_DIM + h0);
    float4 w3 = *(const float4*)(W2 + (size_t)(j4 * 4 + 3) * H_DIM + h0);
#pragma unroll
    for (int i = 0; i < 16; ++i) {
      float4 s4 = *(const float4*)(sst + (rg * 16 + i) * 64 + j4 * 4);
      acc[i].x = fmaf(s4.x, w0.x, fmaf(s4.y, w1.x, fmaf(s4.z, w2.x, fmaf(s4.w, w3.x, acc[i].x))));
      acc[i].y = fmaf(s4.x, w0.y, fmaf(s4.y, w1.y, fmaf(s4.z, w2.y, fmaf(s4.w, w3.y, acc[i].y))));
      acc[i].z = fmaf(s4.x, w0.z, fmaf(s4.y, w1.z, fmaf(s4.z, w2.z, fmaf(s4.w, w3.z, acc[i].z))));
      acc[i].w = fmaf(s4.x, w0.w, fmaf(s4.y, w1.w, fmaf(s4.z, w2.w, fmaf(s4.w, w3.w, acc[i].w))));
    }
  }
  float4 bv = *(const float4*)(b2 + h0);
#pragma unroll
  for (int i = 0; i < 16; ++i) {
    const int r = rbase + rg * 16 + i;
    float4 xv = *(const float4*)(x + (size_t)r * H_DIM + h0);
    float4 o;
    o.x = xv.x + bv.x + acc[i].x;
    o.y = xv.y + bv.y + acc[i].y;
    o.z = xv.z + bv.z + acc[i].z;
    o.w = xv.w + bv.w + acc[i].w;
    *(float4*)(out + (size_t)r * H_DIM + h0) = o;
  }
}

extern "C" void kernel_launch(void* const* d_in, const int* in_sizes, int n_in,
                              void* d_out, int out_size, void* d_ws, size_t ws_size,
                              hipStream_t stream) {
  (void)in_sizes; (void)n_in; (void)out_size; (void)ws_size;
  const float* x   = (const float*)d_in[0];
  const float* W1  = (const float*)d_in[1];
  const float* b1  = (const float*)d_in[2];
  const float* W2  = (const float*)d_in[3];
  const float* b2  = (const float*)d_in[4];
  const float* ph0 = (const float*)d_in[5];
  float* out = (float*)d_out;
  float* ext = (float*)d_ws;                      // 8192*32 fp32 = 1 MB
  float* st  = (float*)d_ws + (size_t)M_ITEMS * NN;  // 8192*64 fp32 = 2 MB

  gemm1_kernel<<<1024, 256, 0, stream>>>(x, W1, b1, ext);
  scan_kernel<<<1, 64, 0, stream>>>(ext, ph0, st);
  gemm2_kernel<<<dim3(16, 128), 256, 0, stream>>>(x, W2, b2, st, out);
}

// Round 2
// 3406.519 us; speedup vs baseline: 1.1980x; 1.1980x over previous
//
#include <hip/hip_runtime.h>
#include <math.h>

#define NN 32
#define DTC 0.01f
#define NSTEPS 10
#define M_ITEMS 8192
#define H_DIM 4096
#define TWO_PI_F 6.28318530717958648f
#define INV_2PI 0.15915494309189535f

// Wave-wide DPP shifts (gfx9-lineage encodings, valid on gfx950):
// 0x138 = wave_shr:1  -> lane i gets lane i-1 (lane 0 gets 0 with bound_ctrl)
// 0x130 = wave_shl:1  -> lane i gets lane i+1 (lane 63 gets 0 with bound_ctrl)
__device__ __forceinline__ float dpp_wshr1(float v) {
  int r = __builtin_amdgcn_update_dpp(0, __builtin_bit_cast(int, v), 0x138, 0xf, 0xf, true);
  return __builtin_bit_cast(float, r);
}
__device__ __forceinline__ float dpp_wshl1(float v) {
  int r = __builtin_amdgcn_update_dpp(0, __builtin_bit_cast(int, v), 0x130, 0xf, 0xf, true);
  return __builtin_bit_cast(float, r);
}

// ---------------- GEMM1: ext[m,n] = tanh(b1[n] + sum_k x[m,k] * W1[k,n]) ----------------
__global__ __launch_bounds__(256) void gemm1_kernel(const float* __restrict__ x,
                                                    const float* __restrict__ W1,
                                                    const float* __restrict__ b1,
                                                    float* __restrict__ ext) {
  __shared__ float part[8][8][NN];
  const int t = threadIdx.x;
  const int wave = t >> 6, lane = t & 63;
  const int n = lane & 31, half = lane >> 5;
  const int r0 = blockIdx.x * 8;
  const int kbase = wave * 1024 + half * 512;
  float acc[8] = {0.f, 0.f, 0.f, 0.f, 0.f, 0.f, 0.f, 0.f};
  const float* xp = x + (size_t)r0 * H_DIM + kbase;
  const float* wp = W1 + (size_t)kbase * NN + n;
#pragma unroll 4
  for (int kk = 0; kk < 512; ++kk) {
    float wv = wp[kk * NN];
#pragma unroll
    for (int j = 0; j < 8; ++j) acc[j] = fmaf(xp[(size_t)j * H_DIM + kk], wv, acc[j]);
  }
#pragma unroll
  for (int j = 0; j < 8; ++j) part[wave * 2 + half][j][n] = acc[j];
  __syncthreads();
  {
    const int j = t >> 5, n2 = t & 31;
    float s = b1[n2];
#pragma unroll
    for (int pi = 0; pi < 8; ++pi) s += part[pi][j][n2];
    ext[(r0 + j) * NN + n2] = tanhf(s);
  }
}

// ---------------- Scan: serial coupled-oscillator recurrence ----------------
// 1 block, 64 threads. node = lane&31. Lanes 32..63 keep a=0 so their s=0,
// which makes wave_shl into lane 31 deliver the correct "no right neighbor" 0.
// q = wrapped phase (revolutions, kept in (-0.002, 1.002)); p = raw radians.
__global__ __launch_bounds__(64, 1) void scan_kernel(const float* __restrict__ ext,
                                                     const float* __restrict__ init_phase,
                                                     float* __restrict__ st) {
  const int lane = threadIdx.x;
  const int node = lane & 31;
  const bool lower = lane < NN;
  const float f = 1.0f + (float)node * (0.5f / 32.0f);
  const float basef_q = DTC * f;              // rev advance from frequency
  const float kq = DTC * 0.5f * INV_2PI;      // coupling -> rev
  const float c2 = DTC * 0.5f;                // coupling -> radians
  const float c_e2q = DTC * INV_2PI;          // ext -> rev
  const float dtl = lower ? DTC : 0.0f;       // masks a-update on upper lanes

  float p = init_phase[node];
  float q = __builtin_amdgcn_fractf(p * INV_2PI);
  float a = lower ? 0.1f : 0.0f;

  // depth-2 ext prefetch pipeline (reads up to 2 items past end -> lands in st
  // region of the workspace: valid memory, values never used in computation)
  float eA = ext[node];
  float eB = ext[NN + node];
  float* stp = st + node;

  for (int it = 0; it < M_ITEMS; ++it) {
    float eC = ext[(it + 2) * NN + node];      // prefetch 2 ahead
    const float base_q = fmaf(c_e2q, eA, basef_q);  // per-step rev advance (const per item)
    const float dext = dtl * eA;
    const float pbc = TWO_PI_F * base_q;       // per-step radian advance (const per item)
#pragma unroll
    for (int si = 0; si < NSTEPS; ++si) {
      float sv = __builtin_amdgcn_sinf(q);             // sin(2*pi*q)
      float fb = __builtin_amdgcn_fractf(q + base_q);  // off critical path
      float pb = p + pbc;                              // off critical path
      float s = a * sv;
      float sl = dpp_wshr1(s);
      float sr = dpp_wshl1(s);
      float coup = sl + sr;                            // (a*sin)@Wc / 0.5
      q = fmaf(kq, coup, fb);                          // wrapped-ish: (-0.002, 1.002)
      p = fmaf(c2, coup, pb);                          // raw radians for output
      float cv = __builtin_amdgcn_cosf(q);             // cos(p_new)
      a = __builtin_amdgcn_fmed3f(fmaf(dext, cv, a), 0.0f, 1.0f);
    }
    if (lower) {
      stp[0] = p;
      stp[NN] = a;
    }
    stp += 2 * NN;
    eA = eB;
    eB = eC;
  }
}

// ---------------- GEMM2: out[m,h] = x[m,h] + b2[h] + sum_j st[m,j]*W2[j,h] ----------------
__global__ __launch_bounds__(256) void gemm2_kernel(const float* __restrict__ x,
                                                    const float* __restrict__ W2,
                                                    const float* __restrict__ b2,
                                                    const float* __restrict__ st,
                                                    float* __restrict__ out) {
  __shared__ float sst[64 * 64];
  const int t = threadIdx.x;
  const int cbase = blockIdx.x * 256;
  const int rbase = blockIdx.y * 64;
  const float4* src = (const float4*)(st + (size_t)rbase * 64);
  float4* dst4 = (float4*)sst;
#pragma unroll
  for (int i = 0; i < 4; ++i) dst4[i * 256 + t] = src[i * 256 + t];
  __syncthreads();
  const int tq = t & 63, rg = t >> 6;
  const int h0 = cbase + tq * 4;
  float4 acc[16];
#pragma unroll
  for (int i = 0; i < 16; ++i) acc[i] = make_float4(0.f, 0.f, 0.f, 0.f);
  for (int j4 = 0; j4 < 16; ++j4) {
    float4 w0 = *(const float4*)(W2 + (size_t)(j4 * 4 + 0) * H_DIM + h0);
    float4 w1 = *(const float4*)(W2 + (size_t)(j4 * 4 + 1) * H_DIM + h0);
    float4 w2 = *(const float4*)(W2 + (size_t)(j4 * 4 + 2) * H_DIM + h0);
    float4 w3 = *(const float4*)(W2 + (size_t)(j4 * 4 + 3) * H_DIM + h0);
#pragma unroll
    for (int i = 0; i < 16; ++i) {
      float4 s4 = *(const float4*)(sst + (rg * 16 + i) * 64 + j4 * 4);
      acc[i].x = fmaf(s4.x, w0.x, fmaf(s4.y, w1.x, fmaf(s4.z, w2.x, fmaf(s4.w, w3.x, acc[i].x))));
      acc[i].y = fmaf(s4.x, w0.y, fmaf(s4.y, w1.y, fmaf(s4.z, w2.y, fmaf(s4.w, w3.y, acc[i].y))));
      acc[i].z = fmaf(s4.x, w0.z, fmaf(s4.y, w1.z, fmaf(s4.z, w2.z, fmaf(s4.w, w3.z, acc[i].z))));
      acc[i].w = fmaf(s4.x, w0.w, fmaf(s4.y, w1.w, fmaf(s4.z, w2.w, fmaf(s4.w, w3.w, acc[i].w))));
    }
  }
  float4 bv = *(const float4*)(b2 + h0);
#pragma unroll
  for (int i = 0; i < 16; ++i) {
    const int r = rbase + rg * 16 + i;
    float4 xv = *(const float4*)(x + (size_t)r * H_DIM + h0);
    float4 o;
    o.x = xv.x + bv.x + acc[i].x;
    o.y = xv.y + bv.y + acc[i].y;
    o.z = xv.z + bv.z + acc[i].z;
    o.w = xv.w + bv.w + acc[i].w;
    *(float4*)(out + (size_t)r * H_DIM + h0) = o;
  }
}

extern "C" void kernel_launch(void* const* d_in, const int* in_sizes, int n_in,
                              void* d_out, int out_size, void* d_ws, size_t ws_size,
                              hipStream_t stream) {
  (void)in_sizes; (void)n_in; (void)out_size; (void)ws_size;
  const float* x   = (const float*)d_in[0];
  const float* W1  = (const float*)d_in[1];
  const float* b1  = (const float*)d_in[2];
  const float* W2  = (const float*)d_in[3];
  const float* b2  = (const float*)d_in[4];
  const float* ph0 = (const float*)d_in[5];
  float* out = (float*)d_out;
  float* ext = (float*)d_ws;                         // 8192*32 fp32 = 1 MB
  float* st  = (float*)d_ws + (size_t)M_ITEMS * NN;  // 8192*64 fp32 = 2 MB

  gemm1_kernel<<<1024, 256, 0, stream>>>(x, W1, b1, ext);
  scan_kernel<<<1, 64, 0, stream>>>(ext, ph0, st);
  gemm2_kernel<<<dim3(16, 128), 256, 0, stream>>>(x, W2, b2, st, out);
}